// Round 1
// baseline (122.172 us; speedup 1.0000x reference)
//
#include <hip/hip_runtime.h>

// Fused: out = ALPHA*x - ALPHA*x^3 + BETA*(N+S+W+E - 4*x), replication-padded
// Shape: (16, 1, 1024, 1024) fp32. Memory-bound: ~134 MB traffic -> ~21 us floor.

#define ALPHA 400.0f
#define BETA  10000.0f

__global__ __launch_bounds__(256) void stencil_kernel(const float* __restrict__ x,
                                                      float* __restrict__ out) {
    constexpr int W = 1024;
    constexpr int H = 1024;

    // one thread = one float4 (4 elems along W); 256 threads cover one row
    const int tid = blockIdx.x * blockDim.x + threadIdx.x;
    const int x4  = (tid & (W / 4 - 1)) << 2;   // 0,4,...,1020
    const int row = tid >> 8;                   // b*H + y
    const int y   = row & (H - 1);
    const size_t img_off = (size_t)(row - y) * W;  // (b*H)*W

    const float* img = x + img_off;

    const int yn = (y == 0)     ? 0     : y - 1;
    const int ys = (y == H - 1) ? H - 1 : y + 1;

    const float4 c = *(const float4*)(img + (size_t)y  * W + x4);
    const float4 n = *(const float4*)(img + (size_t)yn * W + x4);
    const float4 s = *(const float4*)(img + (size_t)ys * W + x4);

    // west/east scalars with replication clamp at image edge
    const float wv = (x4 == 0)     ? c.x : img[(size_t)y * W + x4 - 1];
    const float ev = (x4 == W - 4) ? c.w : img[(size_t)y * W + x4 + 4];

    float4 r;
    r.x = ALPHA * c.x - ALPHA * (c.x * c.x * c.x) + BETA * (n.x + s.x + wv  + c.y - 4.0f * c.x);
    r.y = ALPHA * c.y - ALPHA * (c.y * c.y * c.y) + BETA * (n.y + s.y + c.x + c.z - 4.0f * c.y);
    r.z = ALPHA * c.z - ALPHA * (c.z * c.z * c.z) + BETA * (n.z + s.z + c.y + c.w - 4.0f * c.z);
    r.w = ALPHA * c.w - ALPHA * (c.w * c.w * c.w) + BETA * (n.w + s.w + c.z + ev  - 4.0f * c.w);

    *(float4*)(out + img_off + (size_t)y * W + x4) = r;
}

extern "C" void kernel_launch(void* const* d_in, const int* in_sizes, int n_in,
                              void* d_out, int out_size, void* d_ws, size_t ws_size,
                              hipStream_t stream) {
    const float* x0 = (const float*)d_in[0];
    float* out = (float*)d_out;
    // 16 * 1024 * 1024 elements / 4 per thread / 256 per block = 16384 blocks
    const int n_threads = out_size / 4;
    const int block = 256;
    const int grid = n_threads / block;
    stencil_kernel<<<grid, block, 0, stream>>>(x0, out);
}

// Round 3
// 106.805 us; speedup vs baseline: 1.1439x; 1.1439x over previous
//
#include <hip/hip_runtime.h>

// Fused: out = ALPHA*x - ALPHA*x^3 + BETA*(N+S+W+E - 4*x), replication-padded
// Shape: (16, 1, 1024, 1024) fp32. Memory-bound: ~134 MB HBM traffic -> ~21 us floor.
//
// R1: one block = one row; adjacent rows landed on different XCDs (round-robin
// dispatch), so N/S neighbor-row re-reads missed the per-XCD L2 and hammered L3.
// R2: XCD-aware swizzle gives each XCD a contiguous 2048-row band; the ~256
// concurrently-resident blocks per XCD cover a ~1 MiB sliding window of rows,
// so each row's 3 reads (N/center/S) hit the local 4 MiB L2 after first fetch.
// Output is never re-read -> nontemporal store (clang-native vec type; the HIP
// float4 class is rejected by the builtin).

#define ALPHA 400.0f
#define BETA  10000.0f

typedef float vfloat4 __attribute__((ext_vector_type(4)));

__global__ __launch_bounds__(256) void stencil_kernel(const float* __restrict__ x,
                                                      float* __restrict__ out) {
    constexpr int W = 1024;
    constexpr int H = 1024;
    constexpr int NUM_XCD = 8;

    // XCD swizzle: dispatcher assigns block b -> XCD (b % 8); remap so each
    // XCD processes a contiguous band of rows in order.
    const int band = gridDim.x / NUM_XCD;                     // rows per XCD
    const int row  = (blockIdx.x & (NUM_XCD - 1)) * band + (blockIdx.x >> 3);

    const int x4 = threadIdx.x << 2;                          // 0..1020
    const int y  = row & (H - 1);
    const size_t img_off = (size_t)(row - y) * W;             // (b*H)*W

    const float* img = x + img_off;

    const int yn = (y == 0)     ? 0     : y - 1;
    const int ys = (y == H - 1) ? H - 1 : y + 1;

    const vfloat4 c = *(const vfloat4*)(img + (size_t)y  * W + x4);
    const vfloat4 n = *(const vfloat4*)(img + (size_t)yn * W + x4);
    const vfloat4 s = *(const vfloat4*)(img + (size_t)ys * W + x4);

    // west/east scalars with replication clamp at image edge (L1 hits:
    // same cache lines as neighbor threads' float4 loads)
    const float wv = (x4 == 0)     ? c.x : img[(size_t)y * W + x4 - 1];
    const float ev = (x4 == W - 4) ? c.w : img[(size_t)y * W + x4 + 4];

    vfloat4 r;
    r.x = ALPHA * c.x - ALPHA * (c.x * c.x * c.x) + BETA * (n.x + s.x + wv  + c.y - 4.0f * c.x);
    r.y = ALPHA * c.y - ALPHA * (c.y * c.y * c.y) + BETA * (n.y + s.y + c.x + c.z - 4.0f * c.y);
    r.z = ALPHA * c.z - ALPHA * (c.z * c.z * c.z) + BETA * (n.z + s.z + c.y + c.w - 4.0f * c.z);
    r.w = ALPHA * c.w - ALPHA * (c.w * c.w * c.w) + BETA * (n.w + s.w + c.z + ev  - 4.0f * c.w);

    vfloat4* dst = (vfloat4*)(out + img_off + (size_t)y * W + x4);
    __builtin_nontemporal_store(r, dst);
}

extern "C" void kernel_launch(void* const* d_in, const int* in_sizes, int n_in,
                              void* d_out, int out_size, void* d_ws, size_t ws_size,
                              hipStream_t stream) {
    const float* x0 = (const float*)d_in[0];
    float* out = (float*)d_out;
    // one block per row: 16*1024 = 16384 blocks of 256 threads (4 floats/thread)
    const int grid = out_size / 1024;
    stencil_kernel<<<grid, 256, 0, stream>>>(x0, out);
}